// Round 2
// baseline (253.293 us; speedup 1.0000x reference)
//
#include <hip/hip_runtime.h>
#include <stdint.h>

#define OUT_H 8
#define MAX_W 384
#define MAX_ROI 10
#define FH 160
#define FW 160
#define FC 256

__global__ __launch_bounds__(256) void roi_warp_kernel(
    const float* __restrict__ fm,      // [8,160,160,256] f32
    const float* __restrict__ theta,   // [10,6] f32
    const int* __restrict__ masks,     // [10]
    const int* __restrict__ widths,    // [10]
    float* __restrict__ out)           // [10,8,384,256] f32
{
    const int tx = threadIdx.x;
    const int cg = tx & 63;               // channel group (4 ch each) -> c = 0..252
    const int jj = tx >> 6;               // 0..3
    int b = blockIdx.x;
    const int jt = b % 96;                // 96 j-tiles of 4
    b /= 96;
    const int i   = b & 7;
    const int roi = b >> 3;
    const int j = jt * 4 + jj;
    const int c = cg << 2;

    const int w = widths[roi];
    float* outp = out + ((((size_t)roi * OUT_H + i) * MAX_W + j) * FC + c);

    if (j >= w) {
        float4 z = make_float4(0.f, 0.f, 0.f, 0.f);
        *reinterpret_cast<float4*>(outp) = z;
        return;
    }

    const int bidx = masks[roi];
    const float* tp = theta + roi * 6;
    const float t00 = tp[0];
    const float t01 = tp[1];
    const float t02 = tp[2];
    const float t10 = tp[3];
    const float t11 = tp[4];
    const float t12 = tp[5];

    const int wm1 = (w - 1) > 1 ? (w - 1) : 1;
    const float denom = (float)wm1;
    const float x_t = -1.0f + 2.0f * (float)j / denom;
    const float y_t = -1.0f + 2.0f * (float)i / 7.0f;   // linspace(-1,1,8)[i]

    const float xs = t00 * x_t + t01 * y_t + t02;
    const float ys = t10 * x_t + t11 * y_t + t12;
    const float x = (xs + 1.0f) * ((float)FW * 0.5f);
    const float y = (ys + 1.0f) * ((float)FH * 0.5f);

    const float x0f = floorf(x);
    const float y0f = floorf(y);
    int x0 = (int)x0f;
    int y0 = (int)y0f;
    int x1 = x0 + 1;
    int y1 = y0 + 1;
    x0 = min(max(x0, 0), FW - 1);
    x1 = min(max(x1, 0), FW - 1);
    y0 = min(max(y0, 0), FH - 1);
    y1 = min(max(y1, 0), FH - 1);

    // weight convention exactly as reference (unclipped floor values)
    const float gx0 = (x0f + 1.0f) - x;
    const float gx1 = x - x0f;
    const float gy0 = (y0f + 1.0f) - y;
    const float gy1 = y - y0f;
    const float wa = gx0 * gy0;   // [y0,x0]
    const float wb = gx0 * gy1;   // [y1,x0]
    const float wc = gx1 * gy0;   // [y0,x1]
    const float wd = gx1 * gy1;   // [y1,x1]

    const size_t plane = (size_t)bidx * ((size_t)FH * FW * FC);
    const float* pA = fm + plane + (((size_t)y0 * FW + x0) * FC + c);
    const float* pB = fm + plane + (((size_t)y1 * FW + x0) * FC + c);
    const float* pC = fm + plane + (((size_t)y0 * FW + x1) * FC + c);
    const float* pD = fm + plane + (((size_t)y1 * FW + x1) * FC + c);

    const float4 A = *reinterpret_cast<const float4*>(pA);
    const float4 B = *reinterpret_cast<const float4*>(pB);
    const float4 C = *reinterpret_cast<const float4*>(pC);
    const float4 D = *reinterpret_cast<const float4*>(pD);

    float4 R;
    R.x = wa * A.x + wb * B.x + wc * C.x + wd * D.x;
    R.y = wa * A.y + wb * B.y + wc * C.y + wd * D.y;
    R.z = wa * A.z + wb * B.z + wc * C.z + wd * D.z;
    R.w = wa * A.w + wb * B.w + wc * C.w + wd * D.w;

    *reinterpret_cast<float4*>(outp) = R;
}

extern "C" void kernel_launch(void* const* d_in, const int* in_sizes, int n_in,
                              void* d_out, int out_size, void* d_ws, size_t ws_size,
                              hipStream_t stream) {
    const float* fm     = (const float*)d_in[0];
    const float* theta  = (const float*)d_in[1];
    const int*   masks  = (const int*)d_in[2];
    const int*   widths = (const int*)d_in[3];
    float*       out    = (float*)d_out;

    const int grid = MAX_ROI * OUT_H * (MAX_W / 4);   // 7680 blocks
    roi_warp_kernel<<<grid, 256, 0, stream>>>(fm, theta, masks, widths, out);
}